// Round 1
// baseline (95.428 us; speedup 1.0000x reference)
//
#include <hip/hip_runtime.h>

// FOFE encoding:
//   out[w, c] = sum over positions k with x[w,k]==c && c!=0 of f^(#nonzero strictly after k)
// x: [num_words, 32] int32 (harness passes ints as int32), f: scalar f32,
// out: [num_words, 256] f32.

constexpr int WORD_LEN = 32;
constexpr int VOCAB    = 256;
constexpr int WAVES_PER_BLOCK = 4;   // 256 threads / 64

__global__ __launch_bounds__(256) void fofe_kernel(
    const int* __restrict__ x,
    const float* __restrict__ fptr,
    float* __restrict__ out,
    int num_words)
{
    // one 256-float tile per wave; float4 type guarantees 16B alignment
    __shared__ float4 tile4[WAVES_PER_BLOCK][VOCAB / 4];

    const int lane = threadIdx.x & 63;
    const int wv   = threadIdx.x >> 6;

    int word = blockIdx.x * WAVES_PER_BLOCK + wv;
    // clamp instead of early-return so __syncthreads stays uniform
    // (duplicate waves write identical data to the same word -> benign)
    if (word >= num_words) word = num_words - 1;

    const float f  = *fptr;
    const float lf = __log2f(f);

    // ---- load chars: lanes 0..31, coalesced 128B per wave ----
    int c = 0;
    if (lane < WORD_LEN) c = x[(size_t)word * WORD_LEN + lane];
    const bool nz = (c != 0) && (lane < WORD_LEN);

    // ---- suffix count of nonzero chars strictly after this position ----
    unsigned long long m = __ballot(nz);          // bits 32..63 are 0
    int s = __popcll((m >> lane) >> 1);           // avoid shift-by-64 UB

    // ---- decay weight; s==0 must be exactly 1.0 (matches reference where()) ----
    float w = 0.0f;
    if (nz) w = (s == 0) ? 1.0f : exp2f((float)s * lf);

    // ---- zero this wave's tile (1 KiB, one ds_write_b128 per lane) ----
    float* tf = reinterpret_cast<float*>(tile4[wv]);
    tile4[wv][lane] = make_float4(0.0f, 0.0f, 0.0f, 0.0f);
    __syncthreads();

    // ---- scatter-accumulate (duplicates handled by LDS atomic) ----
    if (nz) atomicAdd(&tf[c], w);
    __syncthreads();

    // ---- write out: wave covers 1 KiB contiguous, fully coalesced ----
    float4 v = tile4[wv][lane];
    float4* o4 = reinterpret_cast<float4*>(out + (size_t)word * VOCAB);
    o4[lane] = v;
}

extern "C" void kernel_launch(void* const* d_in, const int* in_sizes, int n_in,
                              void* d_out, int out_size, void* d_ws, size_t ws_size,
                              hipStream_t stream)
{
    const int*   x    = (const int*)d_in[0];
    const float* fptr = (const float*)d_in[1];
    float*       out  = (float*)d_out;

    const int num_words = in_sizes[0] / WORD_LEN;
    const int blocks = (num_words + WAVES_PER_BLOCK - 1) / WAVES_PER_BLOCK;

    fofe_kernel<<<blocks, 256, 0, stream>>>(x, fptr, out, num_words);
}

// Round 2
// 72.819 us; speedup vs baseline: 1.3105x; 1.3105x over previous
//
#include <hip/hip_runtime.h>

// FOFE encoding:
//   out[w, c] = sum over positions k with x[w,k]==c && c!=0 of f^(#nonzero strictly after k)
// x: [num_words, 32] int32, f: scalar f32, out: [num_words, 256] f32.
//
// Structure: 2048 blocks x 4 waves, grid-stride. Each wave processes 2 words
// per iteration (lanes 0-31 = word A, lanes 32-63 = word B), using a private
// pair of 256-float LDS tiles. No block barriers: LDS ops from a single wave
// complete in order (DS pipe), and each wave owns its tiles exclusively.

constexpr int WORD_LEN = 32;
constexpr int VOCAB    = 256;
constexpr int WAVES_PER_BLOCK = 4;   // 256 threads
constexpr int NUM_BLOCKS      = 2048; // 8 blocks/CU on 256 CUs

__global__ __launch_bounds__(256) void fofe_kernel(
    const int* __restrict__ x,
    const float* __restrict__ fptr,
    float* __restrict__ out,
    int num_words)
{
    // [wave][word-in-pair][vocab] : 8 KiB per block
    __shared__ float tiles[WAVES_PER_BLOCK][2][VOCAB];

    const int lane = threadIdx.x & 63;
    const int wv   = threadIdx.x >> 6;
    const int half = lane >> 5;          // which word of the pair this lane serves
    const int pos  = lane & 31;          // char position within the word

    const int gw     = blockIdx.x * WAVES_PER_BLOCK + wv;  // global wave id
    const int nwaves = NUM_BLOCKS * WAVES_PER_BLOCK;       // 8192
    const int wstride = nwaves * 2;                        // words consumed per step

    const float f  = *fptr;
    const float lf = __log2f(f);

    float*  tile = tiles[wv][half];                       // this lane's word tile
    float4* t4   = reinterpret_cast<float4*>(tiles[wv]);  // both tiles, 128 float4

    // ---- prefetch first pair's chars ----
    int word0 = gw * 2;
    int c = 0;
    if (word0 + half < num_words)
        c = x[(size_t)(word0 + half) * WORD_LEN + pos];

    for (int w0 = word0; w0 < num_words; w0 += wstride) {
        // ---- prefetch next pair (overlaps with LDS work below) ----
        const int wn = w0 + wstride;
        int cn = 0;
        if (wn + half < num_words)
            cn = x[(size_t)(wn + half) * WORD_LEN + pos];

        // ---- suffix count within this lane's half ----
        const bool nz = (c != 0);
        unsigned long long m  = __ballot(nz);
        unsigned int       mh = (unsigned int)(m >> (half * 32));  // this word's 32 bits
        const int s = __popc((mh >> pos) >> 1);  // nonzeros strictly after pos

        float wgt = 0.0f;
        if (nz) wgt = (s == 0) ? 1.0f : exp2f((float)s * lf);

        // ---- zero both tiles: 512 floats = 2 x ds_write_b128 per lane ----
        const float4 z = make_float4(0.0f, 0.0f, 0.0f, 0.0f);
        t4[lane]      = z;
        t4[lane + 64] = z;

        // ---- scatter (wave-private LDS; DS pipe in-order => no barrier) ----
        if (nz) atomicAdd(&tile[c], wgt);

        // ---- read back and store 2 KiB contiguous, fully coalesced ----
        const float4 v0 = t4[lane];        // word w0
        const float4 v1 = t4[lane + 64];   // word w0+1
        if (w0 < num_words)
            reinterpret_cast<float4*>(out + (size_t)w0 * VOCAB)[lane] = v0;
        if (w0 + 1 < num_words)
            reinterpret_cast<float4*>(out + (size_t)(w0 + 1) * VOCAB)[lane] = v1;

        c = cn;
    }
}

extern "C" void kernel_launch(void* const* d_in, const int* in_sizes, int n_in,
                              void* d_out, int out_size, void* d_ws, size_t ws_size,
                              hipStream_t stream)
{
    const int*   x    = (const int*)d_in[0];
    const float* fptr = (const float*)d_in[1];
    float*       out  = (float*)d_out;

    const int num_words = in_sizes[0] / WORD_LEN;

    fofe_kernel<<<NUM_BLOCKS, 256, 0, stream>>>(x, fptr, out, num_words);
}

// Round 3
// 72.077 us; speedup vs baseline: 1.3240x; 1.0103x over previous
//
#include <hip/hip_runtime.h>

// FOFE encoding:
//   out[w, c] = sum over positions k with x[w,k]==c && c!=0 of f^(#nonzero strictly after k)
// x: [num_words, 32] int32, f: scalar f32, out: [num_words, 256] f32.
//
// Structure: 2048 blocks x 4 waves, grid-stride, 4 WORDS per wave-iteration.
// One int2 load per lane covers 4 words' chars (lane i -> word i/16, char
// positions 2*(i&15), 2*(i&15)+1). Four wave-private 256-float LDS tiles per
// wave; no block barriers (DS pipe is in-order per wave, tiles are private).
// Suffix-count of nonzeros from two ballots (even/odd position masks).

constexpr int WORD_LEN = 32;
constexpr int VOCAB    = 256;
constexpr int WAVES_PER_BLOCK = 4;    // 256 threads
constexpr int NUM_BLOCKS      = 2048; // 8 blocks/CU on 256 CUs

__global__ __launch_bounds__(256) void fofe_kernel(
    const int* __restrict__ x,
    const float* __restrict__ fptr,
    float* __restrict__ out,
    int num_words)
{
    // [wave][word-in-quad][vocab] : 16 KiB per block
    __shared__ float tiles[WAVES_PER_BLOCK][4][VOCAB];

    const int lane = threadIdx.x & 63;
    const int wv   = threadIdx.x >> 6;
    const int grp  = lane >> 4;          // which word of the quad (0..3)
    const int j    = lane & 15;          // char-pair index: positions 2j, 2j+1

    const int gw      = blockIdx.x * WAVES_PER_BLOCK + wv;  // global wave id
    const int nwaves  = NUM_BLOCKS * WAVES_PER_BLOCK;       // 8192
    const int wstride = nwaves * 4;                         // words per step

    const float f  = *fptr;
    const float lf = __log2f(f);

    float (*mytiles)[VOCAB] = tiles[wv];
    float*  tile = mytiles[grp];                            // this lane's word tile
    float4* t4   = reinterpret_cast<float4*>(mytiles);      // 256 float4 (all 4 tiles)

    const int2* x2 = reinterpret_cast<const int2*>(x);

    // ---- prefetch first quad's chars (512B contiguous per wave) ----
    int w0 = gw * 4;
    int2 c = make_int2(0, 0);
    if (w0 + grp < num_words)
        c = x2[(size_t)w0 * (WORD_LEN / 2) + lane];

    for (; w0 < num_words; w0 += wstride) {
        // ---- prefetch next quad (overlaps all LDS work below) ----
        const int wn = w0 + wstride;
        int2 cn = make_int2(0, 0);
        if (wn + grp < num_words)
            cn = x2[(size_t)wn * (WORD_LEN / 2) + lane];

        // ---- suffix counts via even/odd ballots, 16-bit slice per word ----
        const bool nzE = (c.x != 0);
        const bool nzO = (c.y != 0);
        const unsigned long long mE = __ballot(nzE);
        const unsigned long long mO = __ballot(nzO);
        const unsigned int mEg = (unsigned int)(mE >> (grp * 16)) & 0xFFFFu;
        const unsigned int mOg = (unsigned int)(mO >> (grp * 16)) & 0xFFFFu;
        // nonzeros strictly after position 2j / 2j+1 within this word:
        const int sE = __popc(mEg >> (j + 1)) + __popc(mOg >> j);
        const int sO = __popc(mEg >> (j + 1)) + __popc(mOg >> (j + 1));

        float wE = 0.0f, wO = 0.0f;
        if (nzE) wE = (sE == 0) ? 1.0f : exp2f((float)sE * lf);
        if (nzO) wO = (sO == 0) ? 1.0f : exp2f((float)sO * lf);

        // ---- zero all 4 tiles: 4 KiB = 4 x ds_write_b128 per lane ----
        const float4 z = make_float4(0.0f, 0.0f, 0.0f, 0.0f);
        t4[lane]       = z;
        t4[lane + 64]  = z;
        t4[lane + 128] = z;
        t4[lane + 192] = z;

        // ---- scatter (wave-private tiles; DS pipe in-order => no barrier) ----
        if (nzE) atomicAdd(&tile[c.x], wE);
        if (nzO) atomicAdd(&tile[c.y], wO);

        // ---- read back & store 4 KiB contiguous, fully coalesced ----
        const float4 v0 = t4[lane];
        const float4 v1 = t4[lane + 64];
        const float4 v2 = t4[lane + 128];
        const float4 v3 = t4[lane + 192];
        float4* o4 = reinterpret_cast<float4*>(out + (size_t)w0 * VOCAB);
        if (w0 + 0 < num_words) o4[lane]       = v0;
        if (w0 + 1 < num_words) o4[lane + 64]  = v1;
        if (w0 + 2 < num_words) o4[lane + 128] = v2;
        if (w0 + 3 < num_words) o4[lane + 192] = v3;

        c = cn;
    }
}

extern "C" void kernel_launch(void* const* d_in, const int* in_sizes, int n_in,
                              void* d_out, int out_size, void* d_ws, size_t ws_size,
                              hipStream_t stream)
{
    const int*   x    = (const int*)d_in[0];
    const float* fptr = (const float*)d_in[1];
    float*       out  = (float*)d_out;

    const int num_words = in_sizes[0] / WORD_LEN;

    fofe_kernel<<<NUM_BLOCKS, 256, 0, stream>>>(x, fptr, out, num_words);
}

// Round 5
// 57.190 us; speedup vs baseline: 1.6686x; 1.2603x over previous
//
#include <hip/hip_runtime.h>

// FOFE encoding:
//   out[w, c] = sum over positions k with x[w,k]==c && c!=0 of f^(#nonzero strictly after k)
// x: [num_words, 32] int32, f: scalar f32, out: [num_words, 256] f32.
//
// Structure: 2048 blocks x 4 waves, grid-stride, 8 words per wave-iteration
// processed as TWO quads with independent register sets (so one quad's
// global-store acks overlap the other quad's DS/VALU work instead of
// serializing on VGPR reuse). Output stores are nontemporal (nt) to bypass
// L2 for the write-once 268 MB stream. Per quad: one int2 load per lane
// covers 4 words' chars; 4 wave-private 256-float LDS tiles; no block
// barriers (DS pipe is in-order per wave, tiles are wave-private).

constexpr int WORD_LEN = 32;
constexpr int VOCAB    = 256;
constexpr int WAVES_PER_BLOCK = 4;    // 256 threads
constexpr int NUM_BLOCKS      = 2048; // 8 blocks/CU on 256 CUs

typedef float f32x4 __attribute__((ext_vector_type(4)));

__global__ __launch_bounds__(256) void fofe_kernel(
    const int* __restrict__ x,
    const float* __restrict__ fptr,
    float* __restrict__ out,
    int num_words)
{
    // [wave][word-in-quad][vocab] : 16 KiB per block (shared by both quads
    // sequentially; DS program order keeps it safe without barriers)
    __shared__ float tiles[WAVES_PER_BLOCK][4][VOCAB];

    const int lane = threadIdx.x & 63;
    const int wv   = threadIdx.x >> 6;
    const int grp  = lane >> 4;          // which word of the quad (0..3)
    const int j    = lane & 15;          // char-pair index: positions 2j, 2j+1

    const int gw      = blockIdx.x * WAVES_PER_BLOCK + wv;  // global wave id
    const int nwaves  = NUM_BLOCKS * WAVES_PER_BLOCK;       // 8192
    const int wstride = nwaves * 8;                         // words per step

    const float f  = *fptr;
    const float lf = __log2f(f);

    float (*mytiles)[VOCAB] = tiles[wv];
    float*  tile = mytiles[grp];                            // this lane's word tile
    f32x4*  t4   = reinterpret_cast<f32x4*>(mytiles);       // 256 f32x4 (all 4 tiles)

    const int2* x2 = reinterpret_cast<const int2*>(x);      // 16 int2 per word

    // process one quad of 4 words whose chars this wave holds in `c`
    auto process = [&](int wq, int2 c) {
        const bool nzE = (c.x != 0);
        const bool nzO = (c.y != 0);
        const unsigned long long mE = __ballot(nzE);
        const unsigned long long mO = __ballot(nzO);
        const unsigned int mEg = (unsigned int)(mE >> (grp * 16)) & 0xFFFFu;
        const unsigned int mOg = (unsigned int)(mO >> (grp * 16)) & 0xFFFFu;
        // nonzeros strictly after position 2j / 2j+1 within this word:
        const int sE = __popc(mEg >> (j + 1)) + __popc(mOg >> j);
        const int sO = __popc(mEg >> (j + 1)) + __popc(mOg >> (j + 1));

        float wE = 0.0f, wO = 0.0f;
        if (nzE) wE = (sE == 0) ? 1.0f : exp2f((float)sE * lf);
        if (nzO) wO = (sO == 0) ? 1.0f : exp2f((float)sO * lf);

        // zero all 4 tiles: 4 KiB = 4 x ds_write_b128 per lane
        const f32x4 z = (f32x4)(0.0f);
        t4[lane]       = z;
        t4[lane + 64]  = z;
        t4[lane + 128] = z;
        t4[lane + 192] = z;

        // scatter (wave-private tiles; DS pipe in-order => no barrier)
        if (nzE) atomicAdd(&tile[c.x], wE);
        if (nzO) atomicAdd(&tile[c.y], wO);

        // read back & stream out 4 KiB contiguous, fully coalesced, nt
        const f32x4 v0 = t4[lane];
        const f32x4 v1 = t4[lane + 64];
        const f32x4 v2 = t4[lane + 128];
        const f32x4 v3 = t4[lane + 192];
        f32x4* o4 = reinterpret_cast<f32x4*>(out + (size_t)wq * VOCAB);
        if (wq + 0 < num_words) __builtin_nontemporal_store(v0, &o4[lane]);
        if (wq + 1 < num_words) __builtin_nontemporal_store(v1, &o4[lane + 64]);
        if (wq + 2 < num_words) __builtin_nontemporal_store(v2, &o4[lane + 128]);
        if (wq + 3 < num_words) __builtin_nontemporal_store(v3, &o4[lane + 192]);
    };

    // ---- prefetch first two quads ----
    int w0 = gw * 8;
    int2 cA = make_int2(0, 0), cB = make_int2(0, 0);
    if (w0 + grp < num_words)     cA = x2[(size_t)w0 * 16 + lane];
    if (w0 + 4 + grp < num_words) cB = x2[(size_t)(w0 + 4) * 16 + lane];

    for (; w0 < num_words; w0 += wstride) {
        // prefetch next iteration's two quads (overlap all work below)
        const int wn = w0 + wstride;
        int2 cAn = make_int2(0, 0), cBn = make_int2(0, 0);
        if (wn + grp < num_words)     cAn = x2[(size_t)wn * 16 + lane];
        if (wn + 4 + grp < num_words) cBn = x2[(size_t)(wn + 4) * 16 + lane];

        process(w0, cA);
        process(w0 + 4, cB);

        cA = cAn;
        cB = cBn;
    }
}

extern "C" void kernel_launch(void* const* d_in, const int* in_sizes, int n_in,
                              void* d_out, int out_size, void* d_ws, size_t ws_size,
                              hipStream_t stream)
{
    const int*   x    = (const int*)d_in[0];
    const float* fptr = (const float*)d_in[1];
    float*       out  = (float*)d_out;

    const int num_words = in_sizes[0] / WORD_LEN;

    fofe_kernel<<<NUM_BLOCKS, 256, 0, stream>>>(x, fptr, out, num_words);
}